// Round 6
// baseline (9085.172 us; speedup 1.0000x reference)
//
#include <hip/hip_runtime.h>
#include <hip/hip_bf16.h>

#define NN 100000
#define EE 500000
#define BB 4096
#define HC 128
#define SCAN_ELEM 1024
#define NSB ((NN + SCAN_ELEM - 1) / SCAN_ELEM)   // 98 blocks

typedef __bf16 bf16_t;
typedef bf16_t bf16x8 __attribute__((ext_vector_type(8)));
typedef float f32x4 __attribute__((ext_vector_type(4)));

__device__ __forceinline__ unsigned short f2bf(float f) {
    unsigned u = __builtin_bit_cast(unsigned, f);
    u += 0x7FFFu + ((u >> 16) & 1u);            // RNE
    return (unsigned short)(u >> 16);
}
__device__ __forceinline__ float bflo(unsigned u) {   // low bf16 -> f32
    return __builtin_bit_cast(float, u << 16);
}
__device__ __forceinline__ float bfhi(unsigned u) {   // high bf16 -> f32
    return __builtin_bit_cast(float, u & 0xFFFF0000u);
}

// ---- convert fp32 -> bf16, 4 elems/thread ----------------------------------
__global__ __launch_bounds__(256) void conv_x(const float* __restrict__ in,
                                              unsigned short* __restrict__ outb,
                                              int total4)
{
    const int g = blockIdx.x * 256 + threadIdx.x;
    if (g >= total4) return;
    const float4 f = *(const float4*)(in + (size_t)g * 4);
    ushort4 u;
    u.x = f2bf(f.x); u.y = f2bf(f.y); u.z = f2bf(f.z); u.w = f2bf(f.w);
    *(ushort4*)(outb + (size_t)g * 4) = u;
}

// ---- convert + transpose weights: W[k,n] fp32 -> Wt[p][n*K+k] bf16 ---------
__global__ __launch_bounds__(256) void prep_w(
    const float* __restrict__ Wq, const float* __restrict__ Wk,
    const float* __restrict__ Wv, const float* __restrict__ Ws,
    unsigned short* __restrict__ Wt, int K)
{
    const int g = blockIdx.x * 256 + threadIdx.x;
    const int per = K * 128;
    if (g >= 4 * per) return;
    const int p = g / per, r = g - p * per;
    const int k = r >> 7, n = r & 127;
    const float* W = p == 0 ? Wq : p == 1 ? Wk : p == 2 ? Wv : Ws;
    Wt[(size_t)p * per + (size_t)n * K + k] = f2bf(W[k * 128 + n]);
}

// ---- MFMA GEMM: block = 4 waves = 4 planes, 32-row tile, 128 cols ----------
// Q,S stored fp32; K,V stored packed bf16 (pair per dword).
__global__ __launch_bounds__(256) void gemm_mfma(
    const unsigned short* __restrict__ A, int K,
    const unsigned short* __restrict__ Wt,
    const float* __restrict__ bq, const float* __restrict__ bk,
    const float* __restrict__ bv, const float* __restrict__ bs,
    float* __restrict__ Q, unsigned* __restrict__ Kb,
    unsigned* __restrict__ Vb, float* __restrict__ S)
{
    const int lane = threadIdx.x & 63;
    const int p = threadIdx.x >> 6;              // wave == plane
    const int m = lane & 15, kq = lane >> 4;
    const int rows0 = blockIdx.x * 32;
    const int nkt = K >> 5;

    const unsigned short* Wp = Wt + (size_t)p * 128 * K;
    const float* bias = p == 0 ? bq : p == 1 ? bk : p == 2 ? bv : bs;

    bf16x8 a[2][4];
#pragma unroll
    for (int mt = 0; mt < 2; mt++)
        for (int kt = 0; kt < nkt; kt++)
            a[mt][kt] = *(const bf16x8*)(A + (size_t)(rows0 + mt * 16 + m) * K + kt * 32 + kq * 8);

    f32x4 acc[2][8];
#pragma unroll
    for (int mt = 0; mt < 2; mt++)
#pragma unroll
        for (int nt = 0; nt < 8; nt++)
            acc[mt][nt] = (f32x4){0.f, 0.f, 0.f, 0.f};

#pragma unroll
    for (int nt = 0; nt < 8; nt++) {
        for (int kt = 0; kt < nkt; kt++) {
            const bf16x8 b = *(const bf16x8*)(Wp + (size_t)(nt * 16 + m) * K + kt * 32 + kq * 8);
            acc[0][nt] = __builtin_amdgcn_mfma_f32_16x16x32_bf16(a[0][kt], b, acc[0][nt], 0, 0, 0);
            acc[1][nt] = __builtin_amdgcn_mfma_f32_16x16x32_bf16(a[1][kt], b, acc[1][nt], 0, 0, 0);
        }
    }

    if (p == 0 || p == 3) {
        float* out = p == 0 ? Q : S;
#pragma unroll
        for (int nt = 0; nt < 8; nt++) {
            const float bi = bias[nt * 16 + m];
#pragma unroll
            for (int mt = 0; mt < 2; mt++) {
                float* o = out + (size_t)(rows0 + mt * 16 + kq * 4) * HC + nt * 16 + m;
#pragma unroll
                for (int r = 0; r < 4; r++) o[r * HC] = acc[mt][nt][r] + bi;
            }
        }
    } else {
        unsigned* out = p == 1 ? Kb : Vb;
#pragma unroll
        for (int nt = 0; nt < 8; nt++) {
            const float bi = bias[nt * 16 + m];
#pragma unroll
            for (int mt = 0; mt < 2; mt++) {
#pragma unroll
                for (int r = 0; r < 4; r++) {
                    const float v0 = acc[mt][nt][r] + bi;
                    const float v1 = __shfl_xor(v0, 1);
                    if (!(m & 1)) {
                        const unsigned pk = (unsigned)f2bf(v0) | ((unsigned)f2bf(v1) << 16);
                        out[(size_t)(rows0 + mt * 16 + kq * 4 + r) * 64 + nt * 8 + (m >> 1)] = pk;
                    }
                }
            }
        }
    }
}

// ---- CSR build: degree histogram -> hierarchical scan -> bucket scatter -----
__global__ __launch_bounds__(256) void deg_k(const int* __restrict__ ei, int* __restrict__ deg)
{
    const int e = blockIdx.x * 256 + threadIdx.x;
    if (e < EE) atomicAdd(&deg[ei[EE + e]], 1);
}

__global__ __launch_bounds__(256) void scan_part(const int* __restrict__ deg,
                                                 int* __restrict__ bsum)
{
    __shared__ int red[256];
    const int base = blockIdx.x * SCAN_ELEM + threadIdx.x * 4;
    int s = 0;
#pragma unroll
    for (int j = 0; j < 4; j++) { const int i = base + j; if (i < NN) s += deg[i]; }
    red[threadIdx.x] = s;
    __syncthreads();
    for (int st = 128; st > 0; st >>= 1) {
        if (threadIdx.x < st) red[threadIdx.x] += red[threadIdx.x + st];
        __syncthreads();
    }
    if (threadIdx.x == 0) bsum[blockIdx.x] = red[0];
}

__global__ __launch_bounds__(128) void scan_top(const int* __restrict__ bsum,
                                                int* __restrict__ boff)
{
    __shared__ int buf[128];
    const int v = (threadIdx.x < NSB) ? bsum[threadIdx.x] : 0;
    buf[threadIdx.x] = v;
    __syncthreads();
    for (int s = 1; s < 128; s <<= 1) {
        const int t = (threadIdx.x >= s) ? buf[threadIdx.x - s] : 0;
        __syncthreads();
        buf[threadIdx.x] += t;
        __syncthreads();
    }
    if (threadIdx.x < NSB) boff[threadIdx.x] = buf[threadIdx.x] - v;
}

__global__ __launch_bounds__(256) void scan_final(const int* __restrict__ deg,
                                                  const int* __restrict__ boff,
                                                  int* __restrict__ off,
                                                  int* __restrict__ cursor)
{
    __shared__ int tsum[256];
    const int base = blockIdx.x * SCAN_ELEM + threadIdx.x * 4;
    int vals[4];
    int s = 0;
#pragma unroll
    for (int j = 0; j < 4; j++) {
        const int i = base + j;
        vals[j] = (i < NN) ? deg[i] : 0;
        s += vals[j];
    }
    tsum[threadIdx.x] = s;
    __syncthreads();
    for (int st = 1; st < 256; st <<= 1) {
        const int t = (threadIdx.x >= st) ? tsum[threadIdx.x - st] : 0;
        __syncthreads();
        tsum[threadIdx.x] += t;
        __syncthreads();
    }
    int ex = boff[blockIdx.x] + tsum[threadIdx.x] - s;
#pragma unroll
    for (int j = 0; j < 4; j++) {
        const int i = base + j;
        if (i < NN) { off[i] = ex; cursor[i] = ex; }
        ex += vals[j];
    }
    if (blockIdx.x == NSB - 1 && threadIdx.x == 255)
        off[NN] = boff[blockIdx.x] + tsum[255];
}

__global__ __launch_bounds__(256) void bucket_k(const int* __restrict__ ei,
                                                int* __restrict__ cursor,
                                                int* __restrict__ eids)
{
    const int e = blockIdx.x * 256 + threadIdx.x;
    if (e < EE) {
        const int d = ei[EE + e];
        const int p = atomicAdd(&cursor[d], 1);
        eids[p] = e;
    }
}

// ---- Fused edge stage: one wave per dst node; K,V gathers are packed bf16. --
__global__ __launch_bounds__(256) void edge_fused(
    const int* __restrict__ ei, const float* __restrict__ ea,
    const float* __restrict__ We,
    const float* __restrict__ Q, const unsigned* __restrict__ Kb,
    const unsigned* __restrict__ Vb,
    const int* __restrict__ off, const int* __restrict__ eids,
    float* __restrict__ H, unsigned short* __restrict__ Hb,
    int do_relu, int wr_bf)
{
    __shared__ float wes[512];
    for (int i = threadIdx.x; i < 512; i += 256) wes[i] = We[i];
    __syncthreads();

    const int lane = threadIdx.x & 63;
    const int n = blockIdx.x * 4 + (threadIdx.x >> 6);
    const int c = lane * 2;
    const float w00 = wes[c],     w10 = wes[128 + c],     w20 = wes[256 + c],     w30 = wes[384 + c];
    const float w01 = wes[c + 1], w11 = wes[128 + c + 1], w21 = wes[256 + c + 1], w31 = wes[384 + c + 1];

    const int beg = off[n], end = off[n + 1];
    const float2 q2 = *(const float2*)(Q + (size_t)n * HC + c);
    float num0 = 0.f, num1 = 0.f, den = 0.f;

    for (int p = beg; p < end; p++) {
        const int e = eids[p];
        const int src = ei[e];
        const float4 a4 = *(const float4*)(ea + (size_t)e * 4);
        const float e0 = a4.x * w00 + a4.y * w10 + a4.z * w20 + a4.w * w30;
        const float e1 = a4.x * w01 + a4.y * w11 + a4.z * w21 + a4.w * w31;
        const unsigned ku = Kb[(size_t)src * 64 + lane];
        float part = q2.x * (bflo(ku) + e0) + q2.y * (bfhi(ku) + e1);
        part += __shfl_xor(part, 1);
        part += __shfl_xor(part, 2);
        part += __shfl_xor(part, 4);
        part += __shfl_xor(part, 8);
        const float al = expf(part * 0.17677669529663687f);  // 1/sqrt(32)
        const unsigned vu = Vb[(size_t)src * 64 + lane];
        num0 += (bflo(vu) + e0) * al;
        num1 += (bfhi(vu) + e1) * al;
        den += al;
    }

    float2* h = (float2*)(H + (size_t)n * HC + c);
    const float2 skip = *h;
    const float inv = 1.f / (den + 1e-16f);
    float o0 = num0 * inv + skip.x;
    float o1 = num1 * inv + skip.y;
    if (do_relu) { o0 = fmaxf(o0, 0.f); o1 = fmaxf(o1, 0.f); }
    *h = make_float2(o0, o1);
    if (wr_bf) {
        const unsigned pk = (unsigned)f2bf(o0) | ((unsigned)f2bf(o1) << 16);
        *(unsigned*)(Hb + (size_t)n * HC + c) = pk;
    }
}

__global__ __launch_bounds__(256) void pool_scatter(
    const float* __restrict__ h, const int* __restrict__ batch,
    float* __restrict__ pooled, float* __restrict__ cnt)
{
    const int gid = blockIdx.x * 256 + threadIdx.x;
    if (gid >= NN * HC) return;
    const int n = gid >> 7;
    const int hc = gid & 127;
    const int b = batch[n];
    atomicAdd(pooled + (size_t)b * HC + hc, h[gid]);
    if (hc == 0) atomicAdd(cnt + b, 1.0f);
}

__global__ __launch_bounds__(256) void head_k(
    const float* __restrict__ pooled, const float* __restrict__ cnt,
    const int* __restrict__ rt, const float* __restrict__ hW,
    const float* __restrict__ hb, float* __restrict__ out)
{
    const int lane = threadIdx.x & 63;
    const int b = blockIdx.x * 4 + (threadIdx.x >> 6);
    if (b >= BB) return;
    const int t = rt[b];
    const int c = lane * 2;
    const float2 p2 = *(const float2*)(pooled + (size_t)b * HC + c);
    const float2 w2 = *(const float2*)(hW + (size_t)t * HC + c);
    float part = p2.x * w2.x + p2.y * w2.y;
    part += __shfl_xor(part, 1);
    part += __shfl_xor(part, 2);
    part += __shfl_xor(part, 4);
    part += __shfl_xor(part, 8);
    part += __shfl_xor(part, 16);
    part += __shfl_xor(part, 32);
    if (lane == 0) out[b] = part / fmaxf(cnt[b], 1.0f) + hb[t];
}

extern "C" void kernel_launch(void* const* d_in, const int* in_sizes, int n_in,
                              void* d_out, int out_size, void* d_ws, size_t ws_size,
                              hipStream_t stream) {
    const float* x      = (const float*)d_in[0];
    const int*   ei     = (const int*)d_in[1];
    const float* ea     = (const float*)d_in[2];
    const int*   batch  = (const int*)d_in[3];
    const int*   rt     = (const int*)d_in[4];

    // workspace layout — ~185 MB
    float* ws     = (float*)d_ws;
    float* Q      = ws;                        // 12,800,000 f
    float* Hbuf   = ws + 12800000;             // 12,800,000 f (S plane / layer output)
    unsigned* Kb  = (unsigned*)(ws + 25600000);// 6,400,000 u32 (packed bf16)
    unsigned* Vb  = Kb + 6400000;              // 6,400,000 u32
    int*   deg    = (int*)(Vb + 6400000);      // 100,000 i
    int*   off    = deg + 100000;              // 100,001 i (+pad)
    int*   cursor = off + 100004;              // 100,000 i
    int*   eids   = cursor + 100000;           // 500,000 i
    int*   bsum   = eids + 500000;             // 128 i
    int*   boff   = bsum + 128;                // 128 i
    unsigned short* Abf = (unsigned short*)(boff + 128);  // 12,800,000 us
    unsigned short* Wt  = Abf + 12800000;                 // 65,536 us
    float* pooled = (float*)(Wt + 65536);      // 524,288 f
    float* cnt    = pooled + 524288;           // 4,096 f

    // ---- CSR build (graph identical every call; ws re-poisoned each call)
    hipMemsetAsync(deg, 0, 100000 * sizeof(int), stream);
    deg_k<<<(EE + 255) / 256, 256, 0, stream>>>(ei, deg);
    scan_part<<<NSB, 256, 0, stream>>>(deg, bsum);
    scan_top<<<1, 128, 0, stream>>>(bsum, boff);
    scan_final<<<NSB, 256, 0, stream>>>(deg, boff, off, cursor);
    bucket_k<<<(EE + 255) / 256, 256, 0, stream>>>(ei, cursor, eids);

    // layer-1 input -> bf16
    conv_x<<<(NN * 64 / 4 + 255) / 256, 256, 0, stream>>>(x, Abf, NN * 64 / 4);

    for (int l = 0; l < 3; l++) {
        const int K = (l == 0) ? 64 : 128;
        const float *Wq, *Wk, *Wv, *Wsk, *bq, *bk, *bv, *bs, *We;
        if (l == 0) {
            Wq = (const float*)d_in[5];  bq = (const float*)d_in[6];
            Wk = (const float*)d_in[7];  bk = (const float*)d_in[8];
            Wv = (const float*)d_in[9];  bv = (const float*)d_in[10];
            We = (const float*)d_in[11];
            Wsk= (const float*)d_in[12]; bs = (const float*)d_in[13];
        } else {
            const int j = l - 1;
            Wq = (const float*)d_in[14] + (size_t)j * HC * HC;  bq = (const float*)d_in[15] + j * HC;
            Wk = (const float*)d_in[16] + (size_t)j * HC * HC;  bk = (const float*)d_in[17] + j * HC;
            Wv = (const float*)d_in[18] + (size_t)j * HC * HC;  bv = (const float*)d_in[19] + j * HC;
            We = (const float*)d_in[20] + (size_t)j * 4 * HC;
            Wsk= (const float*)d_in[21] + (size_t)j * HC * HC;  bs = (const float*)d_in[22] + j * HC;
        }

        prep_w<<<(4 * K * 128 + 255) / 256, 256, 0, stream>>>(Wq, Wk, Wv, Wsk, Wt, K);
        gemm_mfma<<<NN / 32, 256, 0, stream>>>(Abf, K, Wt, bq, bk, bv, bs,
                                               Q, Kb, Vb, Hbuf);
        edge_fused<<<NN / 4, 256, 0, stream>>>(ei, ea, We, Q, Kb, Vb, off, eids,
                                               Hbuf, Abf, l < 2 ? 1 : 0, l < 2 ? 1 : 0);
    }

    hipMemsetAsync(pooled, 0, (size_t)(BB * HC + BB) * sizeof(float), stream);
    pool_scatter<<<(NN * HC) / 256, 256, 0, stream>>>(Hbuf, batch, pooled, cnt);
    head_k<<<BB / 4, 256, 0, stream>>>(pooled, cnt, rt,
        (const float*)d_in[23], (const float*)d_in[24], (float*)d_out);
}

// Round 7
// 854.864 us; speedup vs baseline: 10.6276x; 10.6276x over previous
//
#include <hip/hip_runtime.h>
#include <hip/hip_bf16.h>

#define NN 100000
#define EE 500000
#define BB 4096
#define HC 128
#define SCAN_ELEM 1024
#define NSB ((NN + SCAN_ELEM - 1) / SCAN_ELEM)   // 98 blocks

typedef __bf16 bf16_t;
typedef bf16_t bf16x8 __attribute__((ext_vector_type(8)));
typedef float f32x4 __attribute__((ext_vector_type(4)));

__device__ __forceinline__ unsigned short f2bf(float f) {
    unsigned u = __builtin_bit_cast(unsigned, f);
    u += 0x7FFFu + ((u >> 16) & 1u);            // RNE
    return (unsigned short)(u >> 16);
}
__device__ __forceinline__ float bflo(unsigned u) {   // low bf16 -> f32
    return __builtin_bit_cast(float, u << 16);
}
__device__ __forceinline__ float bfhi(unsigned u) {   // high bf16 -> f32
    return __builtin_bit_cast(float, u & 0xFFFF0000u);
}

// ---- convert fp32 -> bf16, 4 elems/thread ----------------------------------
__global__ __launch_bounds__(256) void conv_x(const float* __restrict__ in,
                                              unsigned short* __restrict__ outb,
                                              int total4)
{
    const int g = blockIdx.x * 256 + threadIdx.x;
    if (g >= total4) return;
    const float4 f = *(const float4*)(in + (size_t)g * 4);
    ushort4 u;
    u.x = f2bf(f.x); u.y = f2bf(f.y); u.z = f2bf(f.z); u.w = f2bf(f.w);
    *(ushort4*)(outb + (size_t)g * 4) = u;
}

// ---- convert + transpose weights: W[k,n] fp32 -> Wt[p][n*K+k] bf16 ---------
__global__ __launch_bounds__(256) void prep_w(
    const float* __restrict__ Wq, const float* __restrict__ Wk,
    const float* __restrict__ Wv, const float* __restrict__ Ws,
    unsigned short* __restrict__ Wt, int K)
{
    const int g = blockIdx.x * 256 + threadIdx.x;
    const int per = K * 128;
    if (g >= 4 * per) return;
    const int p = g / per, r = g - p * per;
    const int k = r >> 7, n = r & 127;
    const float* W = p == 0 ? Wq : p == 1 ? Wk : p == 2 ? Wv : Ws;
    Wt[(size_t)p * per + (size_t)n * K + k] = f2bf(W[k * 128 + n]);
}

// ---- MFMA GEMM: block = 4 waves = 4 planes, 32-row tile, 128 cols ----------
// NKT = K/32 is compile-time so fragment arrays stay in registers.
// Q,S stored fp32; K,V stored packed bf16 (pair per dword).
template<int NKT>
__global__ __launch_bounds__(256) void gemm_mfma(
    const unsigned short* __restrict__ A,
    const unsigned short* __restrict__ Wt,
    const float* __restrict__ bq, const float* __restrict__ bk,
    const float* __restrict__ bv, const float* __restrict__ bs,
    float* __restrict__ Q, unsigned* __restrict__ Kb,
    unsigned* __restrict__ Vb, float* __restrict__ S)
{
    constexpr int K = NKT * 32;
    const int lane = threadIdx.x & 63;
    const int p = threadIdx.x >> 6;              // wave == plane
    const int m = lane & 15, kq = lane >> 4;
    const int rows0 = blockIdx.x * 32;

    const unsigned short* Wp = Wt + (size_t)p * 128 * K;
    const float* bias = p == 0 ? bq : p == 1 ? bk : p == 2 ? bv : bs;

    bf16x8 a[2][NKT];
#pragma unroll
    for (int mt = 0; mt < 2; mt++)
#pragma unroll
        for (int kt = 0; kt < NKT; kt++)
            a[mt][kt] = *(const bf16x8*)(A + (size_t)(rows0 + mt * 16 + m) * K + kt * 32 + kq * 8);

    f32x4 acc[2][8];
#pragma unroll
    for (int mt = 0; mt < 2; mt++)
#pragma unroll
        for (int nt = 0; nt < 8; nt++)
            acc[mt][nt] = (f32x4){0.f, 0.f, 0.f, 0.f};

#pragma unroll
    for (int nt = 0; nt < 8; nt++) {
#pragma unroll
        for (int kt = 0; kt < NKT; kt++) {
            const bf16x8 b = *(const bf16x8*)(Wp + (size_t)(nt * 16 + m) * K + kt * 32 + kq * 8);
            acc[0][nt] = __builtin_amdgcn_mfma_f32_16x16x32_bf16(a[0][kt], b, acc[0][nt], 0, 0, 0);
            acc[1][nt] = __builtin_amdgcn_mfma_f32_16x16x32_bf16(a[1][kt], b, acc[1][nt], 0, 0, 0);
        }
    }

    if (p == 0 || p == 3) {
        float* out = p == 0 ? Q : S;
#pragma unroll
        for (int nt = 0; nt < 8; nt++) {
            const float bi = bias[nt * 16 + m];
#pragma unroll
            for (int mt = 0; mt < 2; mt++) {
                float* o = out + (size_t)(rows0 + mt * 16 + kq * 4) * HC + nt * 16 + m;
#pragma unroll
                for (int r = 0; r < 4; r++) o[r * HC] = acc[mt][nt][r] + bi;
            }
        }
    } else {
        unsigned* out = p == 1 ? Kb : Vb;
#pragma unroll
        for (int nt = 0; nt < 8; nt++) {
            const float bi = bias[nt * 16 + m];
#pragma unroll
            for (int mt = 0; mt < 2; mt++) {
#pragma unroll
                for (int r = 0; r < 4; r++) {
                    const float v0 = acc[mt][nt][r] + bi;
                    const float v1 = __shfl_xor(v0, 1);
                    if (!(m & 1)) {
                        const unsigned pk = (unsigned)f2bf(v0) | ((unsigned)f2bf(v1) << 16);
                        out[(size_t)(rows0 + mt * 16 + kq * 4 + r) * 64 + nt * 8 + (m >> 1)] = pk;
                    }
                }
            }
        }
    }
}

// ---- CSR build: degree histogram -> hierarchical scan -> bucket scatter -----
__global__ __launch_bounds__(256) void deg_k(const int* __restrict__ ei, int* __restrict__ deg)
{
    const int e = blockIdx.x * 256 + threadIdx.x;
    if (e < EE) atomicAdd(&deg[ei[EE + e]], 1);
}

__global__ __launch_bounds__(256) void scan_part(const int* __restrict__ deg,
                                                 int* __restrict__ bsum)
{
    __shared__ int red[256];
    const int base = blockIdx.x * SCAN_ELEM + threadIdx.x * 4;
    int s = 0;
#pragma unroll
    for (int j = 0; j < 4; j++) { const int i = base + j; if (i < NN) s += deg[i]; }
    red[threadIdx.x] = s;
    __syncthreads();
    for (int st = 128; st > 0; st >>= 1) {
        if (threadIdx.x < st) red[threadIdx.x] += red[threadIdx.x + st];
        __syncthreads();
    }
    if (threadIdx.x == 0) bsum[blockIdx.x] = red[0];
}

__global__ __launch_bounds__(128) void scan_top(const int* __restrict__ bsum,
                                                int* __restrict__ boff)
{
    __shared__ int buf[128];
    const int v = (threadIdx.x < NSB) ? bsum[threadIdx.x] : 0;
    buf[threadIdx.x] = v;
    __syncthreads();
    for (int s = 1; s < 128; s <<= 1) {
        const int t = (threadIdx.x >= s) ? buf[threadIdx.x - s] : 0;
        __syncthreads();
        buf[threadIdx.x] += t;
        __syncthreads();
    }
    if (threadIdx.x < NSB) boff[threadIdx.x] = buf[threadIdx.x] - v;
}

__global__ __launch_bounds__(256) void scan_final(const int* __restrict__ deg,
                                                  const int* __restrict__ boff,
                                                  int* __restrict__ off,
                                                  int* __restrict__ cursor)
{
    __shared__ int tsum[256];
    const int base = blockIdx.x * SCAN_ELEM + threadIdx.x * 4;
    int vals[4];
    int s = 0;
#pragma unroll
    for (int j = 0; j < 4; j++) {
        const int i = base + j;
        vals[j] = (i < NN) ? deg[i] : 0;
        s += vals[j];
    }
    tsum[threadIdx.x] = s;
    __syncthreads();
    for (int st = 1; st < 256; st <<= 1) {
        const int t = (threadIdx.x >= st) ? tsum[threadIdx.x - st] : 0;
        __syncthreads();
        tsum[threadIdx.x] += t;
        __syncthreads();
    }
    int ex = boff[blockIdx.x] + tsum[threadIdx.x] - s;
#pragma unroll
    for (int j = 0; j < 4; j++) {
        const int i = base + j;
        if (i < NN) { off[i] = ex; cursor[i] = ex; }
        ex += vals[j];
    }
    if (blockIdx.x == NSB - 1 && threadIdx.x == 255)
        off[NN] = boff[blockIdx.x] + tsum[255];
}

__global__ __launch_bounds__(256) void bucket_k(const int* __restrict__ ei,
                                                int* __restrict__ cursor,
                                                int* __restrict__ eids)
{
    const int e = blockIdx.x * 256 + threadIdx.x;
    if (e < EE) {
        const int d = ei[EE + e];
        const int p = atomicAdd(&cursor[d], 1);
        eids[p] = e;
    }
}

// ---- Fused edge stage: one wave per dst node; K,V gathers are packed bf16. --
__global__ __launch_bounds__(256) void edge_fused(
    const int* __restrict__ ei, const float* __restrict__ ea,
    const float* __restrict__ We,
    const float* __restrict__ Q, const unsigned* __restrict__ Kb,
    const unsigned* __restrict__ Vb,
    const int* __restrict__ off, const int* __restrict__ eids,
    float* __restrict__ H, unsigned short* __restrict__ Hb,
    int do_relu, int wr_bf)
{
    __shared__ float wes[512];
    for (int i = threadIdx.x; i < 512; i += 256) wes[i] = We[i];
    __syncthreads();

    const int lane = threadIdx.x & 63;
    const int n = blockIdx.x * 4 + (threadIdx.x >> 6);
    const int c = lane * 2;
    const float w00 = wes[c],     w10 = wes[128 + c],     w20 = wes[256 + c],     w30 = wes[384 + c];
    const float w01 = wes[c + 1], w11 = wes[128 + c + 1], w21 = wes[256 + c + 1], w31 = wes[384 + c + 1];

    const int beg = off[n], end = off[n + 1];
    const float2 q2 = *(const float2*)(Q + (size_t)n * HC + c);
    float num0 = 0.f, num1 = 0.f, den = 0.f;

    for (int p = beg; p < end; p++) {
        const int e = eids[p];
        const int src = ei[e];
        const float4 a4 = *(const float4*)(ea + (size_t)e * 4);
        const float e0 = a4.x * w00 + a4.y * w10 + a4.z * w20 + a4.w * w30;
        const float e1 = a4.x * w01 + a4.y * w11 + a4.z * w21 + a4.w * w31;
        const unsigned ku = Kb[(size_t)src * 64 + lane];
        float part = q2.x * (bflo(ku) + e0) + q2.y * (bfhi(ku) + e1);
        part += __shfl_xor(part, 1);
        part += __shfl_xor(part, 2);
        part += __shfl_xor(part, 4);
        part += __shfl_xor(part, 8);
        const float al = expf(part * 0.17677669529663687f);  // 1/sqrt(32)
        const unsigned vu = Vb[(size_t)src * 64 + lane];
        num0 += (bflo(vu) + e0) * al;
        num1 += (bfhi(vu) + e1) * al;
        den += al;
    }

    float2* h = (float2*)(H + (size_t)n * HC + c);
    const float2 skip = *h;
    const float inv = 1.f / (den + 1e-16f);
    float o0 = num0 * inv + skip.x;
    float o1 = num1 * inv + skip.y;
    if (do_relu) { o0 = fmaxf(o0, 0.f); o1 = fmaxf(o1, 0.f); }
    *h = make_float2(o0, o1);
    if (wr_bf) {
        const unsigned pk = (unsigned)f2bf(o0) | ((unsigned)f2bf(o1) << 16);
        *(unsigned*)(Hb + (size_t)n * HC + c) = pk;
    }
}

__global__ __launch_bounds__(256) void pool_scatter(
    const float* __restrict__ h, const int* __restrict__ batch,
    float* __restrict__ pooled, float* __restrict__ cnt)
{
    const int gid = blockIdx.x * 256 + threadIdx.x;
    if (gid >= NN * HC) return;
    const int n = gid >> 7;
    const int hc = gid & 127;
    const int b = batch[n];
    atomicAdd(pooled + (size_t)b * HC + hc, h[gid]);
    if (hc == 0) atomicAdd(cnt + b, 1.0f);
}

__global__ __launch_bounds__(256) void head_k(
    const float* __restrict__ pooled, const float* __restrict__ cnt,
    const int* __restrict__ rt, const float* __restrict__ hW,
    const float* __restrict__ hb, float* __restrict__ out)
{
    const int lane = threadIdx.x & 63;
    const int b = blockIdx.x * 4 + (threadIdx.x >> 6);
    if (b >= BB) return;
    const int t = rt[b];
    const int c = lane * 2;
    const float2 p2 = *(const float2*)(pooled + (size_t)b * HC + c);
    const float2 w2 = *(const float2*)(hW + (size_t)t * HC + c);
    float part = p2.x * w2.x + p2.y * w2.y;
    part += __shfl_xor(part, 1);
    part += __shfl_xor(part, 2);
    part += __shfl_xor(part, 4);
    part += __shfl_xor(part, 8);
    part += __shfl_xor(part, 16);
    part += __shfl_xor(part, 32);
    if (lane == 0) out[b] = part / fmaxf(cnt[b], 1.0f) + hb[t];
}

extern "C" void kernel_launch(void* const* d_in, const int* in_sizes, int n_in,
                              void* d_out, int out_size, void* d_ws, size_t ws_size,
                              hipStream_t stream) {
    const float* x      = (const float*)d_in[0];
    const int*   ei     = (const int*)d_in[1];
    const float* ea     = (const float*)d_in[2];
    const int*   batch  = (const int*)d_in[3];
    const int*   rt     = (const int*)d_in[4];

    // workspace layout — ~185 MB
    float* ws     = (float*)d_ws;
    float* Q      = ws;                        // 12,800,000 f
    float* Hbuf   = ws + 12800000;             // 12,800,000 f (S plane / layer output)
    unsigned* Kb  = (unsigned*)(ws + 25600000);// 6,400,000 u32 (packed bf16)
    unsigned* Vb  = Kb + 6400000;              // 6,400,000 u32
    int*   deg    = (int*)(Vb + 6400000);      // 100,000 i
    int*   off    = deg + 100000;              // 100,001 i (+pad)
    int*   cursor = off + 100004;              // 100,000 i
    int*   eids   = cursor + 100000;           // 500,000 i
    int*   bsum   = eids + 500000;             // 128 i
    int*   boff   = bsum + 128;                // 128 i
    unsigned short* Abf = (unsigned short*)(boff + 128);  // 12,800,000 us
    unsigned short* Wt  = Abf + 12800000;                 // 65,536 us
    float* pooled = (float*)(Wt + 65536);      // 524,288 f
    float* cnt    = pooled + 524288;           // 4,096 f

    // ---- CSR build (graph identical every call; ws re-poisoned each call)
    hipMemsetAsync(deg, 0, 100000 * sizeof(int), stream);
    deg_k<<<(EE + 255) / 256, 256, 0, stream>>>(ei, deg);
    scan_part<<<NSB, 256, 0, stream>>>(deg, bsum);
    scan_top<<<1, 128, 0, stream>>>(bsum, boff);
    scan_final<<<NSB, 256, 0, stream>>>(deg, boff, off, cursor);
    bucket_k<<<(EE + 255) / 256, 256, 0, stream>>>(ei, cursor, eids);

    // layer-1 input -> bf16
    conv_x<<<(NN * 64 / 4 + 255) / 256, 256, 0, stream>>>(x, Abf, NN * 64 / 4);

    for (int l = 0; l < 3; l++) {
        const int K = (l == 0) ? 64 : 128;
        const float *Wq, *Wk, *Wv, *Wsk, *bq, *bk, *bv, *bs, *We;
        if (l == 0) {
            Wq = (const float*)d_in[5];  bq = (const float*)d_in[6];
            Wk = (const float*)d_in[7];  bk = (const float*)d_in[8];
            Wv = (const float*)d_in[9];  bv = (const float*)d_in[10];
            We = (const float*)d_in[11];
            Wsk= (const float*)d_in[12]; bs = (const float*)d_in[13];
        } else {
            const int j = l - 1;
            Wq = (const float*)d_in[14] + (size_t)j * HC * HC;  bq = (const float*)d_in[15] + j * HC;
            Wk = (const float*)d_in[16] + (size_t)j * HC * HC;  bk = (const float*)d_in[17] + j * HC;
            Wv = (const float*)d_in[18] + (size_t)j * HC * HC;  bv = (const float*)d_in[19] + j * HC;
            We = (const float*)d_in[20] + (size_t)j * 4 * HC;
            Wsk= (const float*)d_in[21] + (size_t)j * HC * HC;  bs = (const float*)d_in[22] + j * HC;
        }

        prep_w<<<(4 * K * 128 + 255) / 256, 256, 0, stream>>>(Wq, Wk, Wv, Wsk, Wt, K);
        if (K == 64)
            gemm_mfma<2><<<NN / 32, 256, 0, stream>>>(Abf, Wt, bq, bk, bv, bs, Q, Kb, Vb, Hbuf);
        else
            gemm_mfma<4><<<NN / 32, 256, 0, stream>>>(Abf, Wt, bq, bk, bv, bs, Q, Kb, Vb, Hbuf);
        edge_fused<<<NN / 4, 256, 0, stream>>>(ei, ea, We, Q, Kb, Vb, off, eids,
                                               Hbuf, Abf, l < 2 ? 1 : 0, l < 2 ? 1 : 0);
    }

    hipMemsetAsync(pooled, 0, (size_t)(BB * HC + BB) * sizeof(float), stream);
    pool_scatter<<<(NN * HC) / 256, 256, 0, stream>>>(Hbuf, batch, pooled, cnt);
    head_k<<<BB / 4, 256, 0, stream>>>(pooled, cnt, rt,
        (const float*)d_in[23], (const float*)d_in[24], (float*)d_out);
}

// Round 8
// 670.582 us; speedup vs baseline: 13.5482x; 1.2748x over previous
//
#include <hip/hip_runtime.h>
#include <hip/hip_bf16.h>

#define NN 100000
#define EE 500000
#define BB 4096
#define HC 128
#define SCAN_ELEM 1024
#define NSB ((NN + SCAN_ELEM - 1) / SCAN_ELEM)   // 98 blocks

typedef __bf16 bf16_t;
typedef bf16_t bf16x8 __attribute__((ext_vector_type(8)));
typedef float f32x4 __attribute__((ext_vector_type(4)));

__device__ __forceinline__ unsigned short f2bf(float f) {
    unsigned u = __builtin_bit_cast(unsigned, f);
    u += 0x7FFFu + ((u >> 16) & 1u);            // RNE
    return (unsigned short)(u >> 16);
}
__device__ __forceinline__ float bflo(unsigned u) {   // low bf16 -> f32
    return __builtin_bit_cast(float, u << 16);
}
__device__ __forceinline__ float bfhi(unsigned u) {   // high bf16 -> f32
    return __builtin_bit_cast(float, u & 0xFFFF0000u);
}

// ---- convert fp32 -> bf16, 4 elems/thread ----------------------------------
__global__ __launch_bounds__(256) void conv_x(const float* __restrict__ in,
                                              unsigned short* __restrict__ outb,
                                              int total4)
{
    const int g = blockIdx.x * 256 + threadIdx.x;
    if (g >= total4) return;
    const float4 f = *(const float4*)(in + (size_t)g * 4);
    ushort4 u;
    u.x = f2bf(f.x); u.y = f2bf(f.y); u.z = f2bf(f.z); u.w = f2bf(f.w);
    *(ushort4*)(outb + (size_t)g * 4) = u;
}

// ---- convert + transpose weights: W[k,n] fp32 -> Wt[p][n*K+k] bf16 ---------
__global__ __launch_bounds__(256) void prep_w(
    const float* __restrict__ Wq, const float* __restrict__ Wk,
    const float* __restrict__ Wv, const float* __restrict__ Ws,
    unsigned short* __restrict__ Wt, int K)
{
    const int g = blockIdx.x * 256 + threadIdx.x;
    const int per = K * 128;
    if (g >= 4 * per) return;
    const int p = g / per, r = g - p * per;
    const int k = r >> 7, n = r & 127;
    const float* W = p == 0 ? Wq : p == 1 ? Wk : p == 2 ? Wv : Ws;
    Wt[(size_t)p * per + (size_t)n * K + k] = f2bf(W[k * 128 + n]);
}

// ---- MFMA GEMM: block = 4 waves = 4 planes, 32-row tile, 128 cols ----------
// Q,K,V stored packed bf16 (pair per dword); S (skip) stored fp32.
template<int NKT>
__global__ __launch_bounds__(256) void gemm_mfma(
    const unsigned short* __restrict__ A,
    const unsigned short* __restrict__ Wt,
    const float* __restrict__ bq, const float* __restrict__ bk,
    const float* __restrict__ bv, const float* __restrict__ bs,
    unsigned* __restrict__ Qb, unsigned* __restrict__ Kb,
    unsigned* __restrict__ Vb, float* __restrict__ S)
{
    constexpr int K = NKT * 32;
    const int lane = threadIdx.x & 63;
    const int p = threadIdx.x >> 6;              // wave == plane
    const int m = lane & 15, kq = lane >> 4;
    const int rows0 = blockIdx.x * 32;

    const unsigned short* Wp = Wt + (size_t)p * 128 * K;
    const float* bias = p == 0 ? bq : p == 1 ? bk : p == 2 ? bv : bs;

    bf16x8 a[2][NKT];
#pragma unroll
    for (int mt = 0; mt < 2; mt++)
#pragma unroll
        for (int kt = 0; kt < NKT; kt++)
            a[mt][kt] = *(const bf16x8*)(A + (size_t)(rows0 + mt * 16 + m) * K + kt * 32 + kq * 8);

    f32x4 acc[2][8];
#pragma unroll
    for (int mt = 0; mt < 2; mt++)
#pragma unroll
        for (int nt = 0; nt < 8; nt++)
            acc[mt][nt] = (f32x4){0.f, 0.f, 0.f, 0.f};

#pragma unroll
    for (int nt = 0; nt < 8; nt++) {
#pragma unroll
        for (int kt = 0; kt < NKT; kt++) {
            const bf16x8 b = *(const bf16x8*)(Wp + (size_t)(nt * 16 + m) * K + kt * 32 + kq * 8);
            acc[0][nt] = __builtin_amdgcn_mfma_f32_16x16x32_bf16(a[0][kt], b, acc[0][nt], 0, 0, 0);
            acc[1][nt] = __builtin_amdgcn_mfma_f32_16x16x32_bf16(a[1][kt], b, acc[1][nt], 0, 0, 0);
        }
    }

    if (p == 3) {
#pragma unroll
        for (int nt = 0; nt < 8; nt++) {
            const float bi = bias[nt * 16 + m];
#pragma unroll
            for (int mt = 0; mt < 2; mt++) {
                float* o = S + (size_t)(rows0 + mt * 16 + kq * 4) * HC + nt * 16 + m;
#pragma unroll
                for (int r = 0; r < 4; r++) o[r * HC] = acc[mt][nt][r] + bi;
            }
        }
    } else {
        unsigned* out = p == 0 ? Qb : p == 1 ? Kb : Vb;
#pragma unroll
        for (int nt = 0; nt < 8; nt++) {
            const float bi = bias[nt * 16 + m];
#pragma unroll
            for (int mt = 0; mt < 2; mt++) {
#pragma unroll
                for (int r = 0; r < 4; r++) {
                    const float v0 = acc[mt][nt][r] + bi;
                    const float v1 = __shfl_xor(v0, 1);
                    if (!(m & 1)) {
                        const unsigned pk = (unsigned)f2bf(v0) | ((unsigned)f2bf(v1) << 16);
                        out[(size_t)(rows0 + mt * 16 + kq * 4 + r) * 64 + nt * 8 + (m >> 1)] = pk;
                    }
                }
            }
        }
    }
}

// ---- CSR build: degree histogram -> hierarchical scan -> bucket scatter -----
__global__ __launch_bounds__(256) void deg_k(const int* __restrict__ ei, int* __restrict__ deg)
{
    const int e = blockIdx.x * 256 + threadIdx.x;
    if (e < EE) atomicAdd(&deg[ei[EE + e]], 1);
}

__global__ __launch_bounds__(256) void scan_part(const int* __restrict__ deg,
                                                 int* __restrict__ bsum)
{
    __shared__ int red[256];
    const int base = blockIdx.x * SCAN_ELEM + threadIdx.x * 4;
    int s = 0;
#pragma unroll
    for (int j = 0; j < 4; j++) { const int i = base + j; if (i < NN) s += deg[i]; }
    red[threadIdx.x] = s;
    __syncthreads();
    for (int st = 128; st > 0; st >>= 1) {
        if (threadIdx.x < st) red[threadIdx.x] += red[threadIdx.x + st];
        __syncthreads();
    }
    if (threadIdx.x == 0) bsum[blockIdx.x] = red[0];
}

__global__ __launch_bounds__(128) void scan_top(const int* __restrict__ bsum,
                                                int* __restrict__ boff)
{
    __shared__ int buf[128];
    const int v = (threadIdx.x < NSB) ? bsum[threadIdx.x] : 0;
    buf[threadIdx.x] = v;
    __syncthreads();
    for (int s = 1; s < 128; s <<= 1) {
        const int t = (threadIdx.x >= s) ? buf[threadIdx.x - s] : 0;
        __syncthreads();
        buf[threadIdx.x] += t;
        __syncthreads();
    }
    if (threadIdx.x < NSB) boff[threadIdx.x] = buf[threadIdx.x] - v;
}

__global__ __launch_bounds__(256) void scan_final(const int* __restrict__ deg,
                                                  const int* __restrict__ boff,
                                                  int* __restrict__ off,
                                                  int* __restrict__ cursor)
{
    __shared__ int tsum[256];
    const int base = blockIdx.x * SCAN_ELEM + threadIdx.x * 4;
    int vals[4];
    int s = 0;
#pragma unroll
    for (int j = 0; j < 4; j++) {
        const int i = base + j;
        vals[j] = (i < NN) ? deg[i] : 0;
        s += vals[j];
    }
    tsum[threadIdx.x] = s;
    __syncthreads();
    for (int st = 1; st < 256; st <<= 1) {
        const int t = (threadIdx.x >= st) ? tsum[threadIdx.x - st] : 0;
        __syncthreads();
        tsum[threadIdx.x] += t;
        __syncthreads();
    }
    int ex = boff[blockIdx.x] + tsum[threadIdx.x] - s;
#pragma unroll
    for (int j = 0; j < 4; j++) {
        const int i = base + j;
        if (i < NN) { off[i] = ex; cursor[i] = ex; }
        ex += vals[j];
    }
    if (blockIdx.x == NSB - 1 && threadIdx.x == 255)
        off[NN] = boff[blockIdx.x] + tsum[255];
}

// bucket: write src node id AND reordered edge_attr at CSR slot (kills the
// eids->ei indirection and the random ea reads in the hot edge kernel).
__global__ __launch_bounds__(256) void bucket_k(const int* __restrict__ ei,
                                                const float* __restrict__ ea,
                                                int* __restrict__ cursor,
                                                int* __restrict__ esrc,
                                                float4* __restrict__ eaf)
{
    const int e = blockIdx.x * 256 + threadIdx.x;
    if (e < EE) {
        const int d = ei[EE + e];
        const int p = atomicAdd(&cursor[d], 1);
        esrc[p] = ei[e];
        eaf[p] = *(const float4*)(ea + (size_t)e * 4);
    }
}

__global__ __launch_bounds__(256) void cnt_k(const int* __restrict__ batch,
                                             float* __restrict__ cnt)
{
    const int n = blockIdx.x * 256 + threadIdx.x;
    if (n < NN) atomicAdd(&cnt[batch[n]], 1.0f);
}

// ---- Fused edge stage: one wave per dst node; all of Q,K,V packed bf16. -----
// fuse_pool=0: out = relu(msg/den + skip) -> bf16 Hb (next GEMM input).
// fuse_pool=1: out = msg/den + skip -> atomicAdd into pooled[batch[n]].
__global__ __launch_bounds__(256) void edge_fused(
    const int* __restrict__ esrc, const float4* __restrict__ eaf,
    const float* __restrict__ We,
    const unsigned* __restrict__ Qb, const unsigned* __restrict__ Kb,
    const unsigned* __restrict__ Vb,
    const int* __restrict__ off, const float* __restrict__ S,
    unsigned short* __restrict__ Hb,
    const int* __restrict__ batch, float* __restrict__ pooled,
    int fuse_pool)
{
    __shared__ float wes[512];
    for (int i = threadIdx.x; i < 512; i += 256) wes[i] = We[i];
    __syncthreads();

    const int lane = threadIdx.x & 63;
    const int n = blockIdx.x * 4 + (threadIdx.x >> 6);
    const int c = lane * 2;
    const float w00 = wes[c],     w10 = wes[128 + c],     w20 = wes[256 + c],     w30 = wes[384 + c];
    const float w01 = wes[c + 1], w11 = wes[128 + c + 1], w21 = wes[256 + c + 1], w31 = wes[384 + c + 1];

    const int beg = off[n], end = off[n + 1];
    const unsigned qu = Qb[(size_t)n * 64 + lane];
    const float q0 = bflo(qu), q1 = bfhi(qu);
    float num0 = 0.f, num1 = 0.f, den = 0.f;

    int src = 0;
    float4 a4 = make_float4(0.f, 0.f, 0.f, 0.f);
    if (beg < end) { src = esrc[beg]; a4 = eaf[beg]; }

    for (int p = beg; p < end; p++) {
        const unsigned ku = Kb[(size_t)src * 64 + lane];   // issue gathers first,
        const unsigned vu = Vb[(size_t)src * 64 + lane];   // then prefetch next edge
        const float4 ac = a4;
        if (p + 1 < end) { src = esrc[p + 1]; a4 = eaf[p + 1]; }
        const float e0 = ac.x * w00 + ac.y * w10 + ac.z * w20 + ac.w * w30;
        const float e1 = ac.x * w01 + ac.y * w11 + ac.z * w21 + ac.w * w31;
        float part = q0 * (bflo(ku) + e0) + q1 * (bfhi(ku) + e1);
        part += __shfl_xor(part, 1);
        part += __shfl_xor(part, 2);
        part += __shfl_xor(part, 4);
        part += __shfl_xor(part, 8);
        const float al = expf(part * 0.17677669529663687f);  // 1/sqrt(32)
        num0 += (bflo(vu) + e0) * al;
        num1 += (bfhi(vu) + e1) * al;
        den += al;
    }

    const float2 skip = *(const float2*)(S + (size_t)n * HC + c);
    const float inv = 1.f / (den + 1e-16f);
    float o0 = num0 * inv + skip.x;
    float o1 = num1 * inv + skip.y;
    if (!fuse_pool) {
        o0 = fmaxf(o0, 0.f);
        o1 = fmaxf(o1, 0.f);
        const unsigned pk = (unsigned)f2bf(o0) | ((unsigned)f2bf(o1) << 16);
        *(unsigned*)(Hb + (size_t)n * HC + c) = pk;
    } else {
        const int b = batch[n];
        atomicAdd(pooled + (size_t)b * HC + c, o0);
        atomicAdd(pooled + (size_t)b * HC + c + 1, o1);
    }
}

__global__ __launch_bounds__(256) void head_k(
    const float* __restrict__ pooled, const float* __restrict__ cnt,
    const int* __restrict__ rt, const float* __restrict__ hW,
    const float* __restrict__ hb, float* __restrict__ out)
{
    const int lane = threadIdx.x & 63;
    const int b = blockIdx.x * 4 + (threadIdx.x >> 6);
    if (b >= BB) return;
    const int t = rt[b];
    const int c = lane * 2;
    const float2 p2 = *(const float2*)(pooled + (size_t)b * HC + c);
    const float2 w2 = *(const float2*)(hW + (size_t)t * HC + c);
    float part = p2.x * w2.x + p2.y * w2.y;
    part += __shfl_xor(part, 1);
    part += __shfl_xor(part, 2);
    part += __shfl_xor(part, 4);
    part += __shfl_xor(part, 8);
    part += __shfl_xor(part, 16);
    part += __shfl_xor(part, 32);
    if (lane == 0) out[b] = part / fmaxf(cnt[b], 1.0f) + hb[t];
}

extern "C" void kernel_launch(void* const* d_in, const int* in_sizes, int n_in,
                              void* d_out, int out_size, void* d_ws, size_t ws_size,
                              hipStream_t stream) {
    const float* x      = (const float*)d_in[0];
    const int*   ei     = (const int*)d_in[1];
    const float* ea     = (const float*)d_in[2];
    const int*   batch  = (const int*)d_in[3];
    const int*   rt     = (const int*)d_in[4];

    // workspace layout — big 16B-aligned arrays first; ~166 MB total
    float* ws     = (float*)d_ws;
    float* Hbuf   = ws;                                   // 12,800,000 f (S plane)
    unsigned* Qb  = (unsigned*)(ws + 12800000);           // 6,400,000 u32 (packed bf16)
    unsigned* Kb  = Qb + 6400000;                         // 6,400,000
    unsigned* Vb  = Kb + 6400000;                         // 6,400,000
    unsigned short* Abf = (unsigned short*)(Vb + 6400000);// 12,800,000 us
    float4* eaf   = (float4*)(Abf + 12800000);            // 500,000 float4
    unsigned short* Wt = (unsigned short*)(eaf + 500000); // 65,536 us
    float* pooled = (float*)(Wt + 65536);                 // 524,288 f
    float* cnt    = pooled + 524288;                      // 4,096 f
    int*   esrc   = (int*)(cnt + 4096);                   // 500,000 i
    int*   deg    = esrc + 500000;                        // 100,000 i
    int*   off    = deg + 100000;                         // 100,001 i (+pad)
    int*   cursor = off + 100004;                         // 100,000 i
    int*   bsum   = cursor + 100000;                      // 128 i
    int*   boff   = bsum + 128;                           // 128 i

    // ---- CSR build (graph identical every call; ws re-poisoned each call)
    hipMemsetAsync(deg, 0, 100000 * sizeof(int), stream);
    deg_k<<<(EE + 255) / 256, 256, 0, stream>>>(ei, deg);
    scan_part<<<NSB, 256, 0, stream>>>(deg, bsum);
    scan_top<<<1, 128, 0, stream>>>(bsum, boff);
    scan_final<<<NSB, 256, 0, stream>>>(deg, boff, off, cursor);
    bucket_k<<<(EE + 255) / 256, 256, 0, stream>>>(ei, ea, cursor, esrc, eaf);

    // pooled/cnt zero + counts (pooled is written only by layer-3 edge_fused)
    hipMemsetAsync(pooled, 0, (size_t)(BB * HC + BB) * sizeof(float), stream);
    cnt_k<<<(NN + 255) / 256, 256, 0, stream>>>(batch, cnt);

    // layer-1 input -> bf16
    conv_x<<<(NN * 64 / 4 + 255) / 256, 256, 0, stream>>>(x, Abf, NN * 64 / 4);

    for (int l = 0; l < 3; l++) {
        const int K = (l == 0) ? 64 : 128;
        const float *Wq, *Wk, *Wv, *Wsk, *bq, *bk, *bv, *bs, *We;
        if (l == 0) {
            Wq = (const float*)d_in[5];  bq = (const float*)d_in[6];
            Wk = (const float*)d_in[7];  bk = (const float*)d_in[8];
            Wv = (const float*)d_in[9];  bv = (const float*)d_in[10];
            We = (const float*)d_in[11];
            Wsk= (const float*)d_in[12]; bs = (const float*)d_in[13];
        } else {
            const int j = l - 1;
            Wq = (const float*)d_in[14] + (size_t)j * HC * HC;  bq = (const float*)d_in[15] + j * HC;
            Wk = (const float*)d_in[16] + (size_t)j * HC * HC;  bk = (const float*)d_in[17] + j * HC;
            Wv = (const float*)d_in[18] + (size_t)j * HC * HC;  bv = (const float*)d_in[19] + j * HC;
            We = (const float*)d_in[20] + (size_t)j * 4 * HC;
            Wsk= (const float*)d_in[21] + (size_t)j * HC * HC;  bs = (const float*)d_in[22] + j * HC;
        }

        prep_w<<<(4 * K * 128 + 255) / 256, 256, 0, stream>>>(Wq, Wk, Wv, Wsk, Wt, K);
        if (K == 64)
            gemm_mfma<2><<<NN / 32, 256, 0, stream>>>(Abf, Wt, bq, bk, bv, bs, Qb, Kb, Vb, Hbuf);
        else
            gemm_mfma<4><<<NN / 32, 256, 0, stream>>>(Abf, Wt, bq, bk, bv, bs, Qb, Kb, Vb, Hbuf);
        edge_fused<<<NN / 4, 256, 0, stream>>>(esrc, eaf, We, Qb, Kb, Vb, off,
                                               Hbuf, Abf, batch, pooled,
                                               l == 2 ? 1 : 0);
    }

    head_k<<<BB / 4, 256, 0, stream>>>(pooled, cnt, rt,
        (const float*)d_in[23], (const float*)d_in[24], (float*)d_out);
}